// Round 10
// baseline (181.857 us; speedup 1.0000x reference)
//
#include <hip/hip_runtime.h>

// ---------------------------------------------------------------------------
// CVX_Reasoning_Engine — Round 21: per-block ks-rotation (L2 convoy breaker).
//   R20 (persistent ring, LDS-only barriers) won -3.9µs -> 115.6. Remaining
//   theory: all 256 blocks stream the SAME 1MB of packed weights in the SAME
//   order at the SAME rate -> per-XCD, 32 CUs convoy on the same 64B L2 lines;
//   same-address requests serialize on one bank while others idle. R21: each
//   block starts every section's K-loop at a hashed rotation rot_l(b) and
//   wraps; weight addresses AND A-fragment reads rotate together. fp32
//   accumulator makes the K-reorder numerically negligible (~2^-23 vs 0.031
//   bf16 floor). Ring/vwait issue pattern byte-identical; addresses only.
// ---------------------------------------------------------------------------

#define MROWS 16384

typedef __attribute__((ext_vector_type(8))) short bf16x8;   // 8 bf16 = 4 VGPRs
typedef __attribute__((ext_vector_type(4))) float floatx4;

__device__ __forceinline__ unsigned short f2bf(float x) {
    union { float f; unsigned u; } c; c.f = x;
    unsigned r = c.u + 0x7fffu + ((c.u >> 16) & 1u);   // RNE
    return (unsigned short)(r >> 16);
}
__device__ __forceinline__ float bf2f(unsigned short b) {
    union { unsigned u; float f; } c; c.u = ((unsigned)b) << 16;
    return c.f;
}

// --- invisible-to-compiler 16B global load (1 KB/wave) ----------------------
__device__ __forceinline__ bf16x8 gload(const unsigned short* p) {
    bf16x8 r;
    asm volatile("global_load_dwordx4 %0, %1, off"
                 : "=&v"(r)
                 : "v"((unsigned long long)(size_t)p)
                 : "memory");
    return r;
}
// wait until <=IMM vmem outstanding. NO memory clobber (R17-proven).
template<int IMM>
__device__ __forceinline__ void vwait(bf16x8& v) {
    asm volatile("s_waitcnt vmcnt(%1)" : "+v"(v) : "n"(IMM));
}
// TIED drain: keeps every ring register live until vmcnt(0). (R15-proven.)
__device__ __forceinline__ void drain16(bf16x8 (&r)[16]) {
    asm volatile("s_waitcnt vmcnt(0)"
                 : "+v"(r[0]),  "+v"(r[1]),  "+v"(r[2]),  "+v"(r[3]),
                   "+v"(r[4]),  "+v"(r[5]),  "+v"(r[6]),  "+v"(r[7]),
                   "+v"(r[8]),  "+v"(r[9]),  "+v"(r[10]), "+v"(r[11]),
                   "+v"(r[12]), "+v"(r[13]), "+v"(r[14]), "+v"(r[15])
                 :: "memory");
}
// LDS-only barrier: waits ds ops, NOT vmem — weight loads stay in flight.
__device__ __forceinline__ void lds_barrier() {
    asm volatile("s_waitcnt lgkmcnt(0)\n\ts_barrier" ::: "memory");
}

// ---- pack weights -> ks-major fragment-ordered bf16 ------------------------
// W1..W4: T[((ks*NT + ntile)*64 + quad*16 + m_l)*8 + e],  NT = N/16.
// W5: split hi/lo interleaved: T5[(((ks*16 + ntile)*2 + hl)*64 + ...)*8 + e].
__global__ __launch_bounds__(256) void pack_wt(
    const float* __restrict__ W1, unsigned short* __restrict__ T1,
    const float* __restrict__ W2, unsigned short* __restrict__ T2,
    const float* __restrict__ W3, unsigned short* __restrict__ T3,
    const float* __restrict__ W4, unsigned short* __restrict__ T4,
    const float* __restrict__ W5, unsigned short* __restrict__ T5)
{
    const int idx = blockIdx.x * 256 + threadIdx.x;
    if (blockIdx.y == 4) {            // W5: K=64 -> KS=2, N=256
        if (idx >= 2048) return;
        const int k8 = idx >> 8, n = idx & 255;
        const int ks = k8 >> 2, quad = k8 & 3;
        const int ntile = n >> 4, m_l = n & 15;
        unsigned short hi8[8], lo8[8];
        #pragma unroll
        for (int e = 0; e < 8; ++e) {
            const float v = W5[(k8 * 8 + e) * 256 + n];
            const unsigned short hi = f2bf(v);
            hi8[e] = hi; lo8[e] = f2bf(v - bf2f(hi));
        }
        const size_t b = (size_t)(((ks * 16 + ntile) * 2) * 64 + quad * 16 + m_l) * 8;
        *(uint4*)&T5[b]       = *(const uint4*)hi8;
        *(uint4*)&T5[b + 512] = *(const uint4*)lo8;
        return;
    }
    const float* W; unsigned short* T; int Kreal, nshift;
    switch (blockIdx.y) {
        case 0:  W = W1; T = T1; Kreal = 516; nshift = 9; break;
        case 1:  W = W2; T = T2; Kreal = 512; nshift = 8; break;
        case 2:  W = W3; T = T3; Kreal = 256; nshift = 7; break;
        default: W = W4; T = T4; Kreal = 128; nshift = 6; break;
    }
    const int N = 1 << nshift, NT = N >> 4;
    const int KS = (Kreal + 31) >> 5;
    if (idx >= N * KS * 4) return;
    const int k8 = idx >> nshift, n = idx & (N - 1);
    const int ks = k8 >> 2, quad = k8 & 3;
    const int ntile = n >> 4, m_l = n & 15;
    unsigned short t8[8];
    #pragma unroll
    for (int e = 0; e < 8; ++e) {
        const int k = k8 * 8 + e;
        t8[e] = (k < Kreal) ? f2bf(W[(size_t)k * N + n]) : (unsigned short)0;
    }
    *(uint4*)&T[(size_t)((ks * NT + ntile) * 64 + quad * 16 + m_l) * 8] = *(const uint4*)t8;
}

// ---- LDS layout (shorts) — BM=64 rows ---------------------------------------
#define OFF_ZS   0
#define LD_ZS    552
#define OFF_H1   35328
#define LD_H1    520
#define OFF_H2   0
#define LD_H2    264
#define OFF_H3   16896
#define LD_H3    136
#define OFF_H4   25600
#define LD_H4    72
#define OFF_P    35328
#define LD_P     260
#define OFF_BF   68608      // bias floats area (short offset; 4B-aligned)
#define LDS_TOT  71040      // 142080 B <= 160 KiB (1 block/CU)

// per-wave fragment bases for the flat 120-fragment stream
struct WPlan {
    const unsigned short* b0; const unsigned short* b1;
    const unsigned short* b2; const unsigned short* b3;
    const unsigned short* b4;
};
struct Rots { int r1, r2, r3, r4, r5; };
// flat stream: L1 g=[0,68) L2 [68,100) L3 [100,108) L4 [108,112) L5 [112,120)
// per-section ks rotated by R (consume order == this mapping).
__device__ __forceinline__ const unsigned short* frag_addr(
    const WPlan& P, int g, const Rots& R)
{
    if (g >= 120) g = 0;                                   // tail dummies
    if (g < 68)  { const int f = g; int ks = (f >> 2) + R.r1; if (ks >= 17) ks -= 17;
                   return P.b0 + (size_t)(ks * 32 + (f & 3)) * 512; }
    if (g < 100) { const int f = g - 68; int ks = (f >> 1) + R.r2; if (ks >= 16) ks -= 16;
                   return P.b1 + (size_t)(ks * 16 + (f & 1)) * 512; }
    if (g < 108) { const int f = g - 100; int ks = f + R.r3; if (ks >= 8) ks -= 8;
                   return P.b2 + (size_t)(ks * 8) * 512; }
    if (g < 112) { const int f = g - 108; int ks = f + R.r4; if (ks >= 4) ks -= 4;
                   return P.b3 + (size_t)(ks * 4) * 512; }
    { const int f = g - 112; const int ks = (f >> 2) ^ R.r5; const int rem = f & 3;
      return P.b4 + (size_t)ks * 16384 + (size_t)(rem >> 1) * 1024 + (size_t)(rem & 1) * 512; }
}

// one MLP layer as a section of the persistent ring stream, ks-rotated.
template<int MR, int NF, int KSTEPS, int G0>
__device__ __forceinline__ void section(
    bf16x8 (&ring)[16], unsigned short* lds, const WPlan& P, const Rots& R, int rot,
    int offA, int lda, int offC, int ldc,
    const float* bias, int ntile0, int rowbase, int lane)
{
    const int m_l = lane & 15, quad = lane >> 4;
    constexpr int NFR = NF * KSTEPS;
    floatx4 acc[MR][NF];
    #pragma unroll
    for (int j = 0; j < NF; ++j) {
        const float bv = bias[ntile0 * 16 + j * 16 + m_l];   // LDS read (lgkm)
        #pragma unroll
        for (int m = 0; m < MR; ++m)
            acc[m][j] = (floatx4){bv, bv, bv, bv};
    }
    int kse = rot, kse_n = 0;        // rotated ks of current / next group
    bf16x8 a[MR], an[MR];
    #pragma unroll
    for (int m = 0; m < MR; ++m)
        a[m] = *(const bf16x8*)&lds[offA + (rowbase + m*16 + m_l) * lda + kse*32 + quad*8];
    #pragma unroll
    for (int f = 0; f < NFR; ++f) {
        const int ks = f / NF, j = f - ks * NF, g = G0 + f;
        if (j == 0 && ks + 1 < KSTEPS) {       // prefetch next (rotated) group
            kse_n = (kse + 1 == KSTEPS) ? 0 : kse + 1;
            #pragma unroll
            for (int m = 0; m < MR; ++m)
                an[m] = *(const bf16x8*)&lds[offA + (rowbase + m*16 + m_l) * lda + kse_n*32 + quad*8];
        }
        vwait<15>(ring[g & 15]);
        #pragma unroll
        for (int m = 0; m < MR; ++m)
            acc[m][j] = __builtin_amdgcn_mfma_f32_16x16x32_bf16(a[m], ring[g & 15], acc[m][j], 0, 0, 0);
        ring[g & 15] = gload(frag_addr(P, g + 16, R));
        if (j == NF - 1 && ks + 1 < KSTEPS) {  // rotate prefetched A in
            #pragma unroll
            for (int m = 0; m < MR; ++m) a[m] = an[m];
            kse = kse_n;
        }
    }
    // epilogue: lrelu -> bf16 LDS (bias already in acc)
    #pragma unroll
    for (int j = 0; j < NF; ++j) {
        const int col = ntile0 * 16 + j * 16 + m_l;
        #pragma unroll
        for (int m = 0; m < MR; ++m)
            #pragma unroll
            for (int r = 0; r < 4; ++r) {
                float v = acc[m][j][r];
                v = v > 0.f ? v : 0.2f * v;
                lds[offC + (rowbase + m*16 + quad*4 + r) * ldc + col] = f2bf(v);
            }
    }
}

__global__ __launch_bounds__(512, 2) void fused_mlp_qp(
    const float* __restrict__ z, const float* __restrict__ bounds,
    const unsigned short* __restrict__ Wt1, const float* __restrict__ c1,
    const unsigned short* __restrict__ Wt2, const float* __restrict__ c2,
    const unsigned short* __restrict__ Wt3, const float* __restrict__ c3,
    const unsigned short* __restrict__ Wt4, const float* __restrict__ c4,
    const unsigned short* __restrict__ Wt5, const float* __restrict__ c5,
    float* __restrict__ out)
{
    __shared__ unsigned short lds[LDS_TOT];
    const int tid  = threadIdx.x;
    const int wid  = tid >> 6, lane = tid & 63;    // wid 0..7
    const int m_l  = lane & 15, quad = lane >> 4;
    const int bm   = blockIdx.x * 64;

    const float4 bnd = *(const float4*)bounds;

    // per-block rotation hash: desynchronize weight-line phase across blocks
    const unsigned bh = (unsigned)blockIdx.x * 2654435761u;
    Rots R;
    R.r1 = (int)(bh % 17u);
    R.r2 = (int)((bh >> 8) & 15u);
    R.r3 = (int)((bh >> 16) & 7u);
    R.r4 = (int)((bh >> 19) & 3u);
    R.r5 = (int)((bh >> 21) & 1u);

    // ---- per-wave fragment plan + ring fill (issued first; R20) ------------
    WPlan P;
    P.b0 = Wt1 + ((size_t)(wid * 4) * 64 + lane) * 8;
    P.b1 = Wt2 + ((size_t)(wid * 2) * 64 + lane) * 8;
    P.b2 = Wt3 + ((size_t)wid * 64 + lane) * 8;
    P.b3 = Wt4 + ((size_t)(wid & 3) * 64 + lane) * 8;
    P.b4 = Wt5 + (size_t)wid * 2048 + (size_t)lane * 8;

    bf16x8 ring[16];
    #pragma unroll
    for (int f = 0; f < 16; ++f) ring[f] = gload(frag_addr(P, f, R));

    // ---- stage z (64 rows) + biases (1216 floats) to LDS -------------------
    {
        const float4* __restrict__ zf = (const float4*)(z + (size_t)bm * 512);
        #pragma unroll
        for (int i = 0; i < 16; ++i) {
            const int f   = i * 512 + tid;
            const int row = f >> 7, c4i = f & 127;
            const float4 v = zf[f];
            unsigned short t4[4] = {f2bf(v.x), f2bf(v.y), f2bf(v.z), f2bf(v.w)};
            *(uint2*)&lds[OFF_ZS + row * LD_ZS + c4i * 4] = *(uint2*)t4;
        }
        if (tid < 320) {   // cols 512..551: bounds then zeros (64 rows x 5 u4)
            const int row = tid / 5, j = tid % 5;
            unsigned short t8[8] = {0,0,0,0,0,0,0,0};
            if (j == 0) { t8[0] = f2bf(bnd.x); t8[1] = f2bf(bnd.y);
                          t8[2] = f2bf(bnd.z); t8[3] = f2bf(bnd.w); }
            *(uint4*)&lds[OFF_ZS + row * LD_ZS + 512 + j * 8] = *(uint4*)t8;
        }
        float* bfl = (float*)&lds[OFF_BF];
        for (int i = tid; i < 1216; i += 512) {
            float v;
            if      (i < 512)  v = c1[i];
            else if (i < 768)  v = c2[i - 512];
            else if (i < 896)  v = c3[i - 768];
            else if (i < 960)  v = c4[i - 896];
            else               v = c5[i - 960];
            bfl[i] = v;
        }
    }
    lds_barrier();

    // ---- MLP: one persistent ring, LDS-only barriers, rotated sections -----
    const float* bfl = (const float*)&lds[OFF_BF];
    section<4,4,17,  0>(ring, lds, P, R, R.r1, OFF_ZS, LD_ZS, OFF_H1, LD_H1, bfl,       wid*4, 0, lane);
    lds_barrier();
    section<4,2,16, 68>(ring, lds, P, R, R.r2, OFF_H1, LD_H1, OFF_H2, LD_H2, bfl + 512, wid*2, 0, lane);
    lds_barrier();
    section<4,1, 8,100>(ring, lds, P, R, R.r3, OFF_H2, LD_H2, OFF_H3, LD_H3, bfl + 768, wid, 0, lane);
    lds_barrier();
    section<2,1, 4,108>(ring, lds, P, R, R.r4, OFF_H3, LD_H3, OFF_H4, LD_H4, bfl + 896, wid & 3, (wid >> 2) * 32, lane);
    lds_barrier();

    // ---- Layer 5 (g=112..119): split-bf16 hi/lo, rotated ks via XOR --------
    {
        floatx4 acc[4][2];
        #pragma unroll
        for (int j = 0; j < 2; ++j) {
            const float bv = bfl[960 + wid * 32 + j * 16 + m_l];
            #pragma unroll
            for (int m = 0; m < 4; ++m)
                acc[m][j] = (floatx4){bv, bv, bv, bv};
        }
        bf16x8 a[2][4];
        #pragma unroll
        for (int ks = 0; ks < 2; ++ks)
            #pragma unroll
            for (int m = 0; m < 4; ++m)
                a[ks][m] = *(const bf16x8*)&lds[OFF_H4 + (m*16 + m_l) * LD_H4 + ks*32 + quad*8];
        #pragma unroll
        for (int f = 0; f < 8; ++f) {
            const int ks = f >> 2, rem = f & 3, j = rem >> 1, g = 112 + f;
            vwait<15>(ring[g & 15]);
            #pragma unroll
            for (int m = 0; m < 4; ++m) {
                const bf16x8 av = R.r5 ? a[ks ^ 1][m] : a[ks][m];  // compile-time idx both arms
                acc[m][j] = __builtin_amdgcn_mfma_f32_16x16x32_bf16(av, ring[g & 15], acc[m][j], 0, 0, 0);
            }
            ring[g & 15] = gload(frag_addr(P, g + 16, R));   // dummies keep count
        }
        drain16(ring);

        float* __restrict__ p = (float*)&lds[OFF_P];
        #pragma unroll
        for (int j = 0; j < 2; ++j) {
            const int col = wid * 32 + j * 16 + m_l;
            #pragma unroll
            for (int m = 0; m < 4; ++m)
                #pragma unroll
                for (int r = 0; r < 4; ++r)
                    p[(m*16 + quad*4 + r) * LD_P + col] = acc[m][j][r];
        }
    }
    lds_barrier();

    // ---- QP: one row per wave-iteration, contiguous float4 LDS reads -------
    const float b0 = bnd.x, b1 = bnd.y, b2 = bnd.z, b3 = bnd.w;
    const float* __restrict__ p = (const float*)&lds[OFF_P];
    #pragma unroll
    for (int i = 0; i < 8; ++i) {
        const int row = i * 8 + wid;
        const float4 pv = *(const float4*)&p[row * LD_P + lane * 4];
        float xs, wo, ys, ho;
        {
            const float px = pv.x, pw = pv.z;
            const float x0 = fmaxf(px, b0);
            const float g0 = fmaxf(pw, 1.0f);
            const float t  = 0.5f * (b2 - px - pw);
            const float xl = fminf(fmaxf(px + t, b0), b2 - 1.0f);
            const bool over = (x0 + g0) > b2;
            const float x = over ? xl : x0;
            const float g = over ? (b2 - xl) : g0;
            xs = x; wo = x + g;
        }
        {
            const float py = pv.y, ph = pv.w;
            const float x0 = fmaxf(py, b1);
            const float g0 = fmaxf(ph, 1.0f);
            const float t  = 0.5f * (b3 - py - ph);
            const float xl = fminf(fmaxf(py + t, b1), b3 - 1.0f);
            const bool over = (x0 + g0) > b3;
            const float x = over ? xl : x0;
            const float g = over ? (b3 - xl) : g0;
            ys = x; ho = x + g;
        }
        float4 o; o.x = xs; o.y = ys; o.z = wo; o.w = ho;
        ((float4*)out)[(size_t)(bm + row) * 64 + lane] = o;
    }
}

extern "C" void kernel_launch(void* const* d_in, const int* in_sizes, int n_in,
                              void* d_out, int out_size, void* d_ws, size_t ws_size,
                              hipStream_t stream) {
    const float* z      = (const float*)d_in[0];
    const float* bounds = (const float*)d_in[1];
    const float* W1 = (const float*)d_in[2];
    const float* c1 = (const float*)d_in[3];
    const float* W2 = (const float*)d_in[4];
    const float* c2 = (const float*)d_in[5];
    const float* W3 = (const float*)d_in[6];
    const float* c3 = (const float*)d_in[7];
    const float* W4 = (const float*)d_in[8];
    const float* c4 = (const float*)d_in[9];
    const float* W5 = (const float*)d_in[10];
    const float* c5 = (const float*)d_in[11];
    float* out = (float*)d_out;

    unsigned short* ws  = (unsigned short*)d_ws;
    unsigned short* Wt1 = ws;               // 512x544 = 278528
    unsigned short* Wt2 = Wt1 + 278528;     // 256x512 = 131072
    unsigned short* Wt3 = Wt2 + 131072;     // 128x256 = 32768
    unsigned short* Wt4 = Wt3 + 32768;      //  64x128 =  8192
    unsigned short* Wt5 = Wt4 + 8192;       // 256x64x2 = 32768 (hi/lo)

    pack_wt<<<dim3(136, 5), 256, 0, stream>>>(
        W1, Wt1, W2, Wt2, W3, Wt3, W4, Wt4, W5, Wt5);
    fused_mlp_qp<<<dim3(MROWS / 64), 512, 0, stream>>>(
        z, bounds, Wt1, c1, Wt2, c2, Wt3, c3, Wt4, c4, Wt5, c5, out);
}

// Round 11
// 119.567 us; speedup vs baseline: 1.5210x; 1.5210x over previous
//
#include <hip/hip_runtime.h>

// ---------------------------------------------------------------------------
// CVX_Reasoning_Engine — Round 22: revert to R20 (persistent ring, 115.6 µs).
//   R21 post-mortem: per-block ks-rotation DOUBLED the kernel (43->91 µs).
//   (1) Lockstep same-line streaming was optimal, not a hazard: 32 CUs/XCD
//   in phase = 31/32 trailing-edge L2 hits; desync destroyed hit locality
//   (FETCH 20.4->22.7 MB). (2) Runtime Rots un-constant-folded frag_addr:
//   ~15 VALU ops per re-issue on the serialized consume path (VALUBusy
//   11->22%). The weight stream's address schedule must stay compile-time.
//   This file is the R20 state exactly: flat 120-fragment stream through one
//   16-slot ring; vwait<15> per consume; cross-layer prefetch; LDS-only
//   barriers between layers; biases staged to LDS (zero compiler VMEM in the
//   MLP region); ring filled before z-staging; single tied drain16 at end.
// ---------------------------------------------------------------------------

#define MROWS 16384

typedef __attribute__((ext_vector_type(8))) short bf16x8;   // 8 bf16 = 4 VGPRs
typedef __attribute__((ext_vector_type(4))) float floatx4;

__device__ __forceinline__ unsigned short f2bf(float x) {
    union { float f; unsigned u; } c; c.f = x;
    unsigned r = c.u + 0x7fffu + ((c.u >> 16) & 1u);   // RNE
    return (unsigned short)(r >> 16);
}
__device__ __forceinline__ float bf2f(unsigned short b) {
    union { unsigned u; float f; } c; c.u = ((unsigned)b) << 16;
    return c.f;
}

// --- invisible-to-compiler 16B global load (1 KB/wave) ----------------------
__device__ __forceinline__ bf16x8 gload(const unsigned short* p) {
    bf16x8 r;
    asm volatile("global_load_dwordx4 %0, %1, off"
                 : "=&v"(r)
                 : "v"((unsigned long long)(size_t)p)
                 : "memory");
    return r;
}
// wait until <=IMM vmem outstanding. NO memory clobber: the "+v" tie carries
// the real dependence (R17-proven).
template<int IMM>
__device__ __forceinline__ void vwait(bf16x8& v) {
    asm volatile("s_waitcnt vmcnt(%1)" : "+v"(v) : "n"(IMM));
}
// TIED drain: keeps every ring register live until vmcnt(0). (R15-proven.)
__device__ __forceinline__ void drain16(bf16x8 (&r)[16]) {
    asm volatile("s_waitcnt vmcnt(0)"
                 : "+v"(r[0]),  "+v"(r[1]),  "+v"(r[2]),  "+v"(r[3]),
                   "+v"(r[4]),  "+v"(r[5]),  "+v"(r[6]),  "+v"(r[7]),
                   "+v"(r[8]),  "+v"(r[9]),  "+v"(r[10]), "+v"(r[11]),
                   "+v"(r[12]), "+v"(r[13]), "+v"(r[14]), "+v"(r[15])
                 :: "memory");
}
// LDS-only barrier: waits ds ops, NOT vmem — weight loads stay in flight.
__device__ __forceinline__ void lds_barrier() {
    asm volatile("s_waitcnt lgkmcnt(0)\n\ts_barrier" ::: "memory");
}

// ---- pack weights -> ks-major fragment-ordered bf16 ------------------------
// W1..W4: T[((ks*NT + ntile)*64 + quad*16 + m_l)*8 + e],  NT = N/16.
// W5: split hi/lo interleaved: T5[(((ks*16 + ntile)*2 + hl)*64 + ...)*8 + e].
__global__ __launch_bounds__(256) void pack_wt(
    const float* __restrict__ W1, unsigned short* __restrict__ T1,
    const float* __restrict__ W2, unsigned short* __restrict__ T2,
    const float* __restrict__ W3, unsigned short* __restrict__ T3,
    const float* __restrict__ W4, unsigned short* __restrict__ T4,
    const float* __restrict__ W5, unsigned short* __restrict__ T5)
{
    const int idx = blockIdx.x * 256 + threadIdx.x;
    if (blockIdx.y == 4) {            // W5: K=64 -> KS=2, N=256
        if (idx >= 2048) return;
        const int k8 = idx >> 8, n = idx & 255;
        const int ks = k8 >> 2, quad = k8 & 3;
        const int ntile = n >> 4, m_l = n & 15;
        unsigned short hi8[8], lo8[8];
        #pragma unroll
        for (int e = 0; e < 8; ++e) {
            const float v = W5[(k8 * 8 + e) * 256 + n];
            const unsigned short hi = f2bf(v);
            hi8[e] = hi; lo8[e] = f2bf(v - bf2f(hi));
        }
        const size_t b = (size_t)(((ks * 16 + ntile) * 2) * 64 + quad * 16 + m_l) * 8;
        *(uint4*)&T5[b]       = *(const uint4*)hi8;
        *(uint4*)&T5[b + 512] = *(const uint4*)lo8;
        return;
    }
    const float* W; unsigned short* T; int Kreal, nshift;
    switch (blockIdx.y) {
        case 0:  W = W1; T = T1; Kreal = 516; nshift = 9; break;
        case 1:  W = W2; T = T2; Kreal = 512; nshift = 8; break;
        case 2:  W = W3; T = T3; Kreal = 256; nshift = 7; break;
        default: W = W4; T = T4; Kreal = 128; nshift = 6; break;
    }
    const int N = 1 << nshift, NT = N >> 4;
    const int KS = (Kreal + 31) >> 5;
    if (idx >= N * KS * 4) return;
    const int k8 = idx >> nshift, n = idx & (N - 1);
    const int ks = k8 >> 2, quad = k8 & 3;
    const int ntile = n >> 4, m_l = n & 15;
    unsigned short t8[8];
    #pragma unroll
    for (int e = 0; e < 8; ++e) {
        const int k = k8 * 8 + e;
        t8[e] = (k < Kreal) ? f2bf(W[(size_t)k * N + n]) : (unsigned short)0;
    }
    *(uint4*)&T[(size_t)((ks * NT + ntile) * 64 + quad * 16 + m_l) * 8] = *(const uint4*)t8;
}

// ---- LDS layout (shorts) — BM=64 rows ---------------------------------------
#define OFF_ZS   0
#define LD_ZS    552
#define OFF_H1   35328
#define LD_H1    520
#define OFF_H2   0
#define LD_H2    264
#define OFF_H3   16896
#define LD_H3    136
#define OFF_H4   25600
#define LD_H4    72
#define OFF_P    35328
#define LD_P     260
#define OFF_BF   68608      // bias floats area (short offset; 4B-aligned)
#define LDS_TOT  71040      // 142080 B <= 160 KiB (1 block/CU)

// per-wave fragment bases for the flat 120-fragment stream
struct WPlan {
    const unsigned short* b0; const unsigned short* b1;
    const unsigned short* b2; const unsigned short* b3;
    const unsigned short* b4;
};
// flat stream: L1 g=[0,68) L2 [68,100) L3 [100,108) L4 [108,112) L5 [112,120)
__device__ __forceinline__ const unsigned short* frag_addr(const WPlan& P, int g) {
    if (g >= 120) g = 0;                                   // tail dummies
    if (g < 68)  { const int f = g;       return P.b0 + (size_t)((f >> 2) * 32 + (f & 3)) * 512; }
    if (g < 100) { const int f = g - 68;  return P.b1 + (size_t)((f >> 1) * 16 + (f & 1)) * 512; }
    if (g < 108) { const int f = g - 100; return P.b2 + (size_t)(f * 8) * 512; }
    if (g < 112) { const int f = g - 108; return P.b3 + (size_t)(f * 4) * 512; }
    { const int f = g - 112; const int ks = f >> 2, rem = f & 3;
      return P.b4 + (size_t)ks * 16384 + (size_t)(rem >> 1) * 1024 + (size_t)(rem & 1) * 512; }
}

// one MLP layer as a section of the persistent ring stream.
// Consumes g=G0..G0+NF*KSTEPS-1; each consume re-issues frag g+16.
template<int MR, int NF, int KSTEPS, int G0>
__device__ __forceinline__ void section(
    bf16x8 (&ring)[16], unsigned short* lds, const WPlan& P,
    int offA, int lda, int offC, int ldc,
    const float* bias, int ntile0, int rowbase, int lane)
{
    const int m_l = lane & 15, quad = lane >> 4;
    constexpr int NFR = NF * KSTEPS;
    floatx4 acc[MR][NF];
    #pragma unroll
    for (int j = 0; j < NF; ++j) {
        const float bv = bias[ntile0 * 16 + j * 16 + m_l];   // LDS read (lgkm)
        #pragma unroll
        for (int m = 0; m < MR; ++m)
            acc[m][j] = (floatx4){bv, bv, bv, bv};
    }
    bf16x8 a[MR], an[MR];
    #pragma unroll
    for (int m = 0; m < MR; ++m)
        a[m] = *(const bf16x8*)&lds[offA + (rowbase + m*16 + m_l) * lda + quad*8];
    #pragma unroll
    for (int f = 0; f < NFR; ++f) {
        const int ks = f / NF, j = f - ks * NF, g = G0 + f;
        if (j == 0 && ks + 1 < KSTEPS) {       // prefetch next ks-group's A
            #pragma unroll
            for (int m = 0; m < MR; ++m)
                an[m] = *(const bf16x8*)&lds[offA + (rowbase + m*16 + m_l) * lda + (ks+1)*32 + quad*8];
        }
        vwait<15>(ring[g & 15]);
        #pragma unroll
        for (int m = 0; m < MR; ++m)
            acc[m][j] = __builtin_amdgcn_mfma_f32_16x16x32_bf16(a[m], ring[g & 15], acc[m][j], 0, 0, 0);
        ring[g & 15] = gload(frag_addr(P, g + 16));
        if (j == NF - 1 && ks + 1 < KSTEPS) {  // rotate prefetched A in
            #pragma unroll
            for (int m = 0; m < MR; ++m) a[m] = an[m];
        }
    }
    // epilogue: lrelu -> bf16 LDS (bias already in acc)
    #pragma unroll
    for (int j = 0; j < NF; ++j) {
        const int col = ntile0 * 16 + j * 16 + m_l;
        #pragma unroll
        for (int m = 0; m < MR; ++m)
            #pragma unroll
            for (int r = 0; r < 4; ++r) {
                float v = acc[m][j][r];
                v = v > 0.f ? v : 0.2f * v;
                lds[offC + (rowbase + m*16 + quad*4 + r) * ldc + col] = f2bf(v);
            }
    }
}

__global__ __launch_bounds__(512, 2) void fused_mlp_qp(
    const float* __restrict__ z, const float* __restrict__ bounds,
    const unsigned short* __restrict__ Wt1, const float* __restrict__ c1,
    const unsigned short* __restrict__ Wt2, const float* __restrict__ c2,
    const unsigned short* __restrict__ Wt3, const float* __restrict__ c3,
    const unsigned short* __restrict__ Wt4, const float* __restrict__ c4,
    const unsigned short* __restrict__ Wt5, const float* __restrict__ c5,
    float* __restrict__ out)
{
    __shared__ unsigned short lds[LDS_TOT];
    const int tid  = threadIdx.x;
    const int wid  = tid >> 6, lane = tid & 63;    // wid 0..7
    const int m_l  = lane & 15, quad = lane >> 4;
    const int bm   = blockIdx.x * 64;

    const float4 bnd = *(const float4*)bounds;

    // ---- per-wave fragment plan + ring fill (issued FIRST: older-invisible
    // loads make all later compiler vmem waits conservative; fill latency
    // hides under the z/bias staging HBM reads) ------------------------------
    WPlan P;
    P.b0 = Wt1 + ((size_t)(wid * 4) * 64 + lane) * 8;
    P.b1 = Wt2 + ((size_t)(wid * 2) * 64 + lane) * 8;
    P.b2 = Wt3 + ((size_t)wid * 64 + lane) * 8;
    P.b3 = Wt4 + ((size_t)(wid & 3) * 64 + lane) * 8;
    P.b4 = Wt5 + (size_t)wid * 2048 + (size_t)lane * 8;

    bf16x8 ring[16];
    #pragma unroll
    for (int f = 0; f < 16; ++f) ring[f] = gload(frag_addr(P, f));

    // ---- stage z (64 rows) + biases (1216 floats) to LDS -------------------
    {
        const float4* __restrict__ zf = (const float4*)(z + (size_t)bm * 512);
        #pragma unroll
        for (int i = 0; i < 16; ++i) {
            const int f   = i * 512 + tid;
            const int row = f >> 7, c4i = f & 127;
            const float4 v = zf[f];
            unsigned short t4[4] = {f2bf(v.x), f2bf(v.y), f2bf(v.z), f2bf(v.w)};
            *(uint2*)&lds[OFF_ZS + row * LD_ZS + c4i * 4] = *(uint2*)t4;
        }
        if (tid < 320) {   // cols 512..551: bounds then zeros (64 rows x 5 u4)
            const int row = tid / 5, j = tid % 5;
            unsigned short t8[8] = {0,0,0,0,0,0,0,0};
            if (j == 0) { t8[0] = f2bf(bnd.x); t8[1] = f2bf(bnd.y);
                          t8[2] = f2bf(bnd.z); t8[3] = f2bf(bnd.w); }
            *(uint4*)&lds[OFF_ZS + row * LD_ZS + 512 + j * 8] = *(uint4*)t8;
        }
        float* bf = (float*)&lds[OFF_BF];
        for (int i = tid; i < 1216; i += 512) {
            float v;
            if      (i < 512)  v = c1[i];
            else if (i < 768)  v = c2[i - 512];
            else if (i < 896)  v = c3[i - 768];
            else               v = (i < 960) ? c4[i - 896] : c5[i - 960];
            bf[i] = v;
        }
    }
    lds_barrier();

    // ---- MLP: one persistent ring, LDS-only barriers between layers --------
    const float* bf = (const float*)&lds[OFF_BF];
    section<4,4,17,  0>(ring, lds, P, OFF_ZS, LD_ZS, OFF_H1, LD_H1, bf,       wid*4, 0, lane);
    lds_barrier();
    section<4,2,16, 68>(ring, lds, P, OFF_H1, LD_H1, OFF_H2, LD_H2, bf + 512, wid*2, 0, lane);
    lds_barrier();
    section<4,1, 8,100>(ring, lds, P, OFF_H2, LD_H2, OFF_H3, LD_H3, bf + 768, wid, 0, lane);
    lds_barrier();
    section<2,1, 4,108>(ring, lds, P, OFF_H3, LD_H3, OFF_H4, LD_H4, bf + 896, wid & 3, (wid >> 2) * 32, lane);
    lds_barrier();

    // ---- Layer 5 (g=112..119): split-bf16 hi/lo, whole A-set upfront -------
    {
        floatx4 acc[4][2];
        #pragma unroll
        for (int j = 0; j < 2; ++j) {
            const float bv = bf[960 + wid * 32 + j * 16 + m_l];
            #pragma unroll
            for (int m = 0; m < 4; ++m)
                acc[m][j] = (floatx4){bv, bv, bv, bv};
        }
        bf16x8 a[2][4];
        #pragma unroll
        for (int ks = 0; ks < 2; ++ks)
            #pragma unroll
            for (int m = 0; m < 4; ++m)
                a[ks][m] = *(const bf16x8*)&lds[OFF_H4 + (m*16 + m_l) * LD_H4 + ks*32 + quad*8];
        #pragma unroll
        for (int f = 0; f < 8; ++f) {
            const int ks = f >> 2, rem = f & 3, j = rem >> 1, g = 112 + f;
            vwait<15>(ring[g & 15]);
            #pragma unroll
            for (int m = 0; m < 4; ++m)
                acc[m][j] = __builtin_amdgcn_mfma_f32_16x16x32_bf16(a[ks][m], ring[g & 15], acc[m][j], 0, 0, 0);
            ring[g & 15] = gload(frag_addr(P, g + 16));   // dummies keep count
        }
        drain16(ring);

        float* __restrict__ p = (float*)&lds[OFF_P];
        #pragma unroll
        for (int j = 0; j < 2; ++j) {
            const int col = wid * 32 + j * 16 + m_l;
            #pragma unroll
            for (int m = 0; m < 4; ++m)
                #pragma unroll
                for (int r = 0; r < 4; ++r)
                    p[(m*16 + quad*4 + r) * LD_P + col] = acc[m][j][r];
        }
    }
    lds_barrier();

    // ---- QP: one row per wave-iteration, contiguous float4 LDS reads -------
    const float b0 = bnd.x, b1 = bnd.y, b2 = bnd.z, b3 = bnd.w;
    const float* __restrict__ p = (const float*)&lds[OFF_P];
    #pragma unroll
    for (int i = 0; i < 8; ++i) {
        const int row = i * 8 + wid;
        const float4 pv = *(const float4*)&p[row * LD_P + lane * 4];
        float xs, wo, ys, ho;
        {
            const float px = pv.x, pw = pv.z;
            const float x0 = fmaxf(px, b0);
            const float g0 = fmaxf(pw, 1.0f);
            const float t  = 0.5f * (b2 - px - pw);
            const float xl = fminf(fmaxf(px + t, b0), b2 - 1.0f);
            const bool over = (x0 + g0) > b2;
            const float x = over ? xl : x0;
            const float g = over ? (b2 - xl) : g0;
            xs = x; wo = x + g;
        }
        {
            const float py = pv.y, ph = pv.w;
            const float x0 = fmaxf(py, b1);
            const float g0 = fmaxf(ph, 1.0f);
            const float t  = 0.5f * (b3 - py - ph);
            const float xl = fminf(fmaxf(py + t, b1), b3 - 1.0f);
            const bool over = (x0 + g0) > b3;
            const float x = over ? xl : x0;
            const float g = over ? (b3 - xl) : g0;
            ys = x; ho = x + g;
        }
        float4 o; o.x = xs; o.y = ys; o.z = wo; o.w = ho;
        ((float4*)out)[(size_t)(bm + row) * 64 + lane] = o;
    }
}

extern "C" void kernel_launch(void* const* d_in, const int* in_sizes, int n_in,
                              void* d_out, int out_size, void* d_ws, size_t ws_size,
                              hipStream_t stream) {
    const float* z      = (const float*)d_in[0];
    const float* bounds = (const float*)d_in[1];
    const float* W1 = (const float*)d_in[2];
    const float* c1 = (const float*)d_in[3];
    const float* W2 = (const float*)d_in[4];
    const float* c2 = (const float*)d_in[5];
    const float* W3 = (const float*)d_in[6];
    const float* c3 = (const float*)d_in[7];
    const float* W4 = (const float*)d_in[8];
    const float* c4 = (const float*)d_in[9];
    const float* W5 = (const float*)d_in[10];
    const float* c5 = (const float*)d_in[11];
    float* out = (float*)d_out;

    unsigned short* ws  = (unsigned short*)d_ws;
    unsigned short* Wt1 = ws;               // 512x544 = 278528
    unsigned short* Wt2 = Wt1 + 278528;     // 256x512 = 131072
    unsigned short* Wt3 = Wt2 + 131072;     // 128x256 = 32768
    unsigned short* Wt4 = Wt3 + 32768;      //  64x128 =  8192
    unsigned short* Wt5 = Wt4 + 8192;       // 256x64x2 = 32768 (hi/lo)

    pack_wt<<<dim3(136, 5), 256, 0, stream>>>(
        W1, Wt1, W2, Wt2, W3, Wt3, W4, Wt4, W5, Wt5);
    fused_mlp_qp<<<dim3(MROWS / 64), 512, 0, stream>>>(
        z, bounds, Wt1, c1, Wt2, c2, Wt3, c3, Wt4, c4, Wt5, c5, out);
}